// Round 23
// baseline (48.466 us; speedup 1.0000x reference)
//
#include <hip/hip_runtime.h>

#define NH 8
#define ND 64
#define NM 32
#define NCH_I 16   // fine (intra) sub-chunk size
#define NC_I  64   // fine sub-chunk count
#define NCH 32     // coarse (final) chunk size
#define NC  32     // coarse chunk count

typedef float f32x4 __attribute__((ext_vector_type(4)));

// ---- 16-lane-group allreduce, pure VALU butterfly (no readlane) ----
__device__ __forceinline__ float grp16_sum(float x) {
    x += __int_as_float(__builtin_amdgcn_update_dpp(0, __float_as_int(x), 0xB1, 0xf, 0xf, false));
    x += __int_as_float(__builtin_amdgcn_update_dpp(0, __float_as_int(x), 0x4E, 0xf, 0xf, false));
    x += __int_as_float(__builtin_amdgcn_update_dpp(0, __float_as_int(x), 0x141, 0xf, 0xf, false));
    x += __int_as_float(__builtin_amdgcn_update_dpp(0, __float_as_int(x), 0x140, 0xf, 0xf, false));
    return x;
}

// ---- 64-lane reduce (DPP rows + readlane bcast) ----
__device__ __forceinline__ float wave_sum_bcast(float x) {
    float s = x;
    s += __int_as_float(__builtin_amdgcn_update_dpp(0, __float_as_int(s), 0x111, 0xf, 0xf, false));
    s += __int_as_float(__builtin_amdgcn_update_dpp(0, __float_as_int(s), 0x112, 0xf, 0xf, false));
    s += __int_as_float(__builtin_amdgcn_update_dpp(0, __float_as_int(s), 0x114, 0xf, 0xf, false));
    s += __int_as_float(__builtin_amdgcn_update_dpp(0, __float_as_int(s), 0x118, 0xf, 0xf, false));
    s += __int_as_float(__builtin_amdgcn_update_dpp(0, __float_as_int(s), 0x142, 0xa, 0xf, false));
    s += __int_as_float(__builtin_amdgcn_update_dpp(0, __float_as_int(s), 0x143, 0xc, 0xf, false));
    return __int_as_float(__builtin_amdgcn_readlane(__float_as_int(s), 63));
}

// ---------------- Kernel 1: fine intra scan (NCH_I=16), 16-lane groups ----------------
// 512 blocks x 512 threads (2 blocks/CU, 4 waves/SIMD); block = one fine sub-chunk.
__global__ __launch_bounds__(512) void intra_kernel(
    const float* __restrict__ A_bar, const float* __restrict__ K,
    const float* __restrict__ V, const float* __restrict__ beta,
    float* __restrict__ totalA_f, float* __restrict__ buf_f)
{
    __shared__ float K_l[NCH_I][ND], A_l[NCH_I][ND], V_l[NCH_I][ND], b_l[NCH_I];
    const int gh = blockIdx.x;       // gf*NH + hh
    const int hh = gh & (NH - 1);
    const int gf = gh >> 3;          // 0..63
    const int tid = threadIdx.x;

    {   // stage: 256 stagers x float4 per array
        if (tid < NCH_I * 16) {
            const int f = tid * 4;
            const int t = f >> 6, off = f & 63;
            const int row = ((gf * NCH_I + t) * NH + hh) * 64 + off;
            *(float4*)&K_l[t][off] = *(const float4*)(K + row);
            *(float4*)&A_l[t][off] = *(const float4*)(A_bar + row);
            *(float4*)&V_l[t][off] = *(const float4*)(V + row);
        }
        if (tid < NCH_I) b_l[tid] = beta[(gf * NCH_I + tid) * NH + hh];
        __syncthreads();
    }

    const int lane = tid & 63;
    const int r = lane >> 4, j = lane & 15;
    const int m = (tid >> 6) * 4 + r;            // 0..31

    float hr0 = 0.f, hr1 = 0.f, hr2 = 0.f, hr3 = 0.f;
    float hi0 = 0.f, hi1 = 0.f, hi2 = 0.f, hi3 = 0.f;
    float cr = 1.f, ci = 0.f;

#pragma unroll 4
    for (int t = 0; t < NCH_I; ++t) {
        const float4 k4 = *(const float4*)(&K_l[t][4 * j]);
        const float2 a2 = *(const float2*)(&A_l[t][2 * m]);
        const float2 v2 = *(const float2*)(&V_l[t][2 * m]);
        const float  b  = b_l[t];

        float sr = (hr0 * k4.x + hr1 * k4.y) + (hr2 * k4.z + hr3 * k4.w);
        float si = (hi0 * k4.x + hi1 * k4.y) + (hi2 * k4.z + hi3 * k4.w);
        sr = grp16_sum(sr);
        si = grp16_sum(si);

        const float bk0 = b * k4.x, bk1 = b * k4.y, bk2 = b * k4.z, bk3 = b * k4.w;
        float tr, ti;
        tr = hr0 - bk0 * sr; ti = hi0 - bk0 * si;
        hr0 = a2.x * tr - a2.y * ti + bk0 * v2.x;
        hi0 = a2.x * ti + a2.y * tr + bk0 * v2.y;
        tr = hr1 - bk1 * sr; ti = hi1 - bk1 * si;
        hr1 = a2.x * tr - a2.y * ti + bk1 * v2.x;
        hi1 = a2.x * ti + a2.y * tr + bk1 * v2.y;
        tr = hr2 - bk2 * sr; ti = hi2 - bk2 * si;
        hr2 = a2.x * tr - a2.y * ti + bk2 * v2.x;
        hi2 = a2.x * ti + a2.y * tr + bk2 * v2.y;
        tr = hr3 - bk3 * sr; ti = hi3 - bk3 * si;
        hr3 = a2.x * tr - a2.y * ti + bk3 * v2.x;
        hi3 = a2.x * ti + a2.y * tr + bk3 * v2.y;

        const float n = cr * a2.x - ci * a2.y;
        ci = cr * a2.y + ci * a2.x;
        cr = n;
    }

    // fine summaries, planar stride 128: entry e = gh*NM + m
    const int e = gh * NM + m;
    *(float4*)&buf_f[e * 128 + 4 * j]      = make_float4(hr0, hr1, hr2, hr3);
    *(float4*)&buf_f[e * 128 + 64 + 4 * j] = make_float4(hi0, hi1, hi2, hi3);
    if (j == 0) {
        totalA_f[2 * e]     = cr;
        totalA_f[2 * e + 1] = ci;
    }
}

// ---------------- Kernel 2: combine pairs of fine summaries -> coarse (NCH=32) ----------------
// Thread per (g,hh,m,d): s_c = a1*h0 + h1 ; A_c = a0*a1. 524288 threads.
__global__ __launch_bounds__(256) void combine_kernel(
    const float* __restrict__ totalA_f, const float* __restrict__ buf_f,
    float* __restrict__ totalA_c, float* __restrict__ buf_c)
{
    const int t   = blockIdx.x * 256 + threadIdx.x;
    const int d   = t & 63;
    const int m   = (t >> 6) & 31;
    const int hh  = (t >> 11) & 7;
    const int g   = t >> 14;                     // 0..31

    const int e0 = ((2 * g) * NH + hh) * NM + m;
    const int e1 = ((2 * g + 1) * NH + hh) * NM + m;
    const int ec = (g * NH + hh) * NM + m;

    const float a1r = totalA_f[2 * e1], a1i = totalA_f[2 * e1 + 1];
    const float h0r = buf_f[e0 * 128 + d],      h0i = buf_f[e0 * 128 + 64 + d];
    const float h1r = buf_f[e1 * 128 + d],      h1i = buf_f[e1 * 128 + 64 + d];

    buf_c[ec * 128 + d]      = a1r * h0r - a1i * h0i + h1r;
    buf_c[ec * 128 + 64 + d] = a1r * h0i + a1i * h0r + h1i;

    if (d == 0) {
        const float a0r = totalA_f[2 * e0], a0i = totalA_f[2 * e0 + 1];
        totalA_c[2 * ec]     = a0r * a1r - a0i * a1i;
        totalA_c[2 * ec + 1] = a0r * a1i + a0i * a1r;
    }
}

// ---------------- Kernel 3: single-m 64-lane waves, prefix + final scan (R19, unchanged) ----------------
__global__ __launch_bounds__(256) void final_kernel(
    const float* __restrict__ A_bar, const float* __restrict__ K,
    const float* __restrict__ V, const float* __restrict__ beta,
    const float* __restrict__ totalA, const float* __restrict__ buf,
    float* __restrict__ Y)
{
    __shared__ float K_l[NCH][ND];
    __shared__ float A_l[NCH][8], V_l[NCH][8];
    __shared__ float b_l[NCH];

    const int blk  = blockIdx.x;         // 0..2047
    const int gh   = blk >> 3;           // g*NH + hh
    const int mblk = blk & 7;
    const int hh   = gh & (NH - 1);
    const int g    = gh >> 3;
    const int tid  = threadIdx.x;
    const int wv   = tid >> 6;
    const int lane = tid & 63;
    const int m    = mblk * 4 + wv;

    {   // stage: K full; A/V slice cols [8*mblk, 8*mblk+8); beta
        const int f = tid * 8;
        const int t = f >> 6, off = f & 63;
        const int row = ((g * NCH + t) * NH + hh) * 64 + off;
        *(float4*)&K_l[t][off]     = *(const float4*)(K + row);
        *(float4*)&K_l[t][off + 4] = *(const float4*)(K + row + 4);
        const int t2 = tid >> 3, c = tid & 7;
        const int row2 = ((g * NCH + t2) * NH + hh) * 64 + 8 * mblk + c;
        A_l[t2][c] = A_bar[row2];
        V_l[t2][c] = V[row2];
        if (tid < NCH) b_l[tid] = beta[(g * NCH + tid) * NH + hh];
        __syncthreads();
    }

    // prefix for this m: fold s = A_gg * s + H_gg over coarse gg < g
    float hr = 0.f, hi = 0.f;
#pragma unroll 4
    for (int gg = 0; gg < g; ++gg) {
        const int e = (gg * NH + hh) * NM + m;
        const float ar = totalA[2 * e], ai = totalA[2 * e + 1];
        const float fr = buf[e * 128 + lane];
        const float fi = buf[e * 128 + 64 + lane];
        const float n = ar * hr - ai * hi + fr;
        hi = ar * hi + ai * hr + fi;
        hr = n;
    }

    // final scan with init = s_in; state IS the output
    const int base_l = g * NCH;
    const int c0 = 2 * wv;
#pragma unroll 4
    for (int t = 0; t < NCH; ++t) {
        const float kd = K_l[t][lane];
        const float b  = b_l[t];
        const float ar = A_l[t][c0], ai = A_l[t][c0 + 1];
        const float vr = V_l[t][c0], vi = V_l[t][c0 + 1];
        const float bk = b * kd;

        const float hkr = wave_sum_bcast(hr * kd);
        const float hki = wave_sum_bcast(hi * kd);

        const float tr = hr - bk * hkr, ti = hi - bk * hki;
        hr = ar * tr - ai * ti + bk * vr;
        hi = ar * ti + ai * tr + bk * vi;

        // Y[b,l,h,2m,d]=Re, Y[b,l,h,2m+1,d]=Im — 256 B/wave contiguous stores
        const int ybase = ((base_l + t) * NH + hh) * (2 * NM) * ND + lane;
        __builtin_nontemporal_store(hr, &Y[ybase + (2 * m) * ND]);
        __builtin_nontemporal_store(hi, &Y[ybase + (2 * m + 1) * ND]);
    }
}

extern "C" void kernel_launch(void* const* d_in, const int* in_sizes, int n_in,
                              void* d_out, int out_size, void* d_ws, size_t ws_size,
                              hipStream_t stream) {
    const float* A_bar = (const float*)d_in[0];
    const float* K     = (const float*)d_in[1];
    const float* V     = (const float*)d_in[2];
    const float* beta  = (const float*)d_in[3];
    float* Y = (float*)d_out;

    // ws: totalA_f (32768) | buf_f (2,097,152) | totalA_c (16384) | buf_c (1,048,576) ≈ 12.8 MB
    float* ws = (float*)d_ws;
    float* totalA_f = ws;
    float* buf_f    = ws + 32768;
    float* totalA_c = ws + 32768 + 2097152;
    float* buf_c    = ws + 32768 + 2097152 + 16384;

    intra_kernel<<<NC_I * NH, 512, 0, stream>>>(A_bar, K, V, beta, totalA_f, buf_f);
    combine_kernel<<<2048, 256, 0, stream>>>(totalA_f, buf_f, totalA_c, buf_c);
    final_kernel<<<NC * NH * 8, 256, 0, stream>>>(A_bar, K, V, beta, totalA_c, buf_c, Y);
}

// Round 24
// 44.081 us; speedup vs baseline: 1.0995x; 1.0995x over previous
//
#include <hip/hip_runtime.h>

#define NH 8
#define ND 64
#define NM 32
#define NCH 32   // sub-chunk size
#define NC 32    // num sub-chunks

typedef float f32x4 __attribute__((ext_vector_type(4)));

// ---- 16-lane-group allreduce, pure VALU butterfly (no readlane) ----
__device__ __forceinline__ float grp16_sum(float x) {
    x += __int_as_float(__builtin_amdgcn_update_dpp(0, __float_as_int(x), 0xB1, 0xf, 0xf, false));
    x += __int_as_float(__builtin_amdgcn_update_dpp(0, __float_as_int(x), 0x4E, 0xf, 0xf, false));
    x += __int_as_float(__builtin_amdgcn_update_dpp(0, __float_as_int(x), 0x141, 0xf, 0xf, false));
    x += __int_as_float(__builtin_amdgcn_update_dpp(0, __float_as_int(x), 0x140, 0xf, 0xf, false));
    return x;
}

// ---- 64-lane reduce (DPP rows + readlane bcast) ----
__device__ __forceinline__ float wave_sum_bcast(float x) {
    float s = x;
    s += __int_as_float(__builtin_amdgcn_update_dpp(0, __float_as_int(s), 0x111, 0xf, 0xf, false));
    s += __int_as_float(__builtin_amdgcn_update_dpp(0, __float_as_int(s), 0x112, 0xf, 0xf, false));
    s += __int_as_float(__builtin_amdgcn_update_dpp(0, __float_as_int(s), 0x114, 0xf, 0xf, false));
    s += __int_as_float(__builtin_amdgcn_update_dpp(0, __float_as_int(s), 0x118, 0xf, 0xf, false));
    s += __int_as_float(__builtin_amdgcn_update_dpp(0, __float_as_int(s), 0x142, 0xa, 0xf, false));
    s += __int_as_float(__builtin_amdgcn_update_dpp(0, __float_as_int(s), 0x143, 0xc, 0xf, false));
    return __int_as_float(__builtin_amdgcn_readlane(__float_as_int(s), 63));
}

// ---------------- Kernel A: intra scan, 16-lane groups (R15/R19 winner + tweaks) ----------------
// 248 blocks x 512 threads (g=31's summary is never consumed).
__global__ __launch_bounds__(512) void intra_kernel(
    const float* __restrict__ A_bar, const float* __restrict__ K,
    const float* __restrict__ V, const float* __restrict__ beta,
    float* __restrict__ totalA, float* __restrict__ buf)
{
    __shared__ float K_l[NCH][ND], A_l[NCH][ND], V_l[NCH][ND], b_l[NCH];
    const int gh = blockIdx.x;       // g*NH + hh ; g < 31
    const int hh = gh & (NH - 1);
    const int g  = gh >> 3;
    const int tid = threadIdx.x;

    {   // stage (512 float4 stagers)
        const int f = tid * 4;
        const int t = f >> 6, off = f & 63;
        const int row = ((g * NCH + t) * NH + hh) * 64 + off;
        *(float4*)&K_l[t][off] = *(const float4*)(K + row);
        *(float4*)&A_l[t][off] = *(const float4*)(A_bar + row);
        *(float4*)&V_l[t][off] = *(const float4*)(V + row);
        if (tid < NCH) b_l[tid] = beta[(g * NCH + tid) * NH + hh];
        __syncthreads();
    }

    const int lane = tid & 63;
    const int r = lane >> 4, j = lane & 15;
    const int m = (tid >> 6) * 4 + r;            // 0..31

    float hr0 = 0.f, hr1 = 0.f, hr2 = 0.f, hr3 = 0.f;
    float hi0 = 0.f, hi1 = 0.f, hi2 = 0.f, hi3 = 0.f;
    float cr = 1.f, ci = 0.f;

#pragma unroll 8
    for (int t = 0; t < NCH; ++t) {
        const float4 k4 = *(const float4*)(&K_l[t][4 * j]);
        const float2 a2 = *(const float2*)(&A_l[t][2 * m]);
        const float2 v2 = *(const float2*)(&V_l[t][2 * m]);
        const float  b  = b_l[t];

        float sr = (hr0 * k4.x + hr1 * k4.y) + (hr2 * k4.z + hr3 * k4.w);
        float si = (hi0 * k4.x + hi1 * k4.y) + (hi2 * k4.z + hi3 * k4.w);
        sr = grp16_sum(sr);
        si = grp16_sum(si);

        const float bk0 = b * k4.x, bk1 = b * k4.y, bk2 = b * k4.z, bk3 = b * k4.w;
        float tr, ti;
        tr = hr0 - bk0 * sr; ti = hi0 - bk0 * si;
        hr0 = a2.x * tr - a2.y * ti + bk0 * v2.x;
        hi0 = a2.x * ti + a2.y * tr + bk0 * v2.y;
        tr = hr1 - bk1 * sr; ti = hi1 - bk1 * si;
        hr1 = a2.x * tr - a2.y * ti + bk1 * v2.x;
        hi1 = a2.x * ti + a2.y * tr + bk1 * v2.y;
        tr = hr2 - bk2 * sr; ti = hi2 - bk2 * si;
        hr2 = a2.x * tr - a2.y * ti + bk2 * v2.x;
        hi2 = a2.x * ti + a2.y * tr + bk2 * v2.y;
        tr = hr3 - bk3 * sr; ti = hi3 - bk3 * si;
        hr3 = a2.x * tr - a2.y * ti + bk3 * v2.x;
        hi3 = a2.x * ti + a2.y * tr + bk3 * v2.y;

        const float n = cr * a2.x - ci * a2.y;
        ci = cr * a2.y + ci * a2.x;
        cr = n;
    }

    const int base_m = gh * NM + m;              // entry id
    *(float4*)&buf[base_m * 128 + 4 * j]      = make_float4(hr0, hr1, hr2, hr3);
    *(float4*)&buf[base_m * 128 + 64 + 4 * j] = make_float4(hi0, hi1, hi2, hi3);
    if (j == 0) {
        totalA[2 * base_m]     = cr;
        totalA[2 * base_m + 1] = ci;
    }
}

// ---------------- Kernel B: single-m 64-lane waves, prefix (pipelined) + final scan ----------------
__global__ __launch_bounds__(256) void final_kernel(
    const float* __restrict__ A_bar, const float* __restrict__ K,
    const float* __restrict__ V, const float* __restrict__ beta,
    const float* __restrict__ totalA, const float* __restrict__ buf,
    float* __restrict__ Y)
{
    __shared__ float K_l[NCH][ND];
    __shared__ float A_l[NCH][8], V_l[NCH][8];
    __shared__ float b_l[NCH];

    const int blk  = blockIdx.x;         // 0..2047
    const int gh   = blk >> 3;           // g*NH + hh
    const int mblk = blk & 7;
    const int hh   = gh & (NH - 1);
    const int g    = gh >> 3;
    const int tid  = threadIdx.x;
    const int wv   = tid >> 6;
    const int lane = tid & 63;
    const int m    = mblk * 4 + wv;

    {   // stage: K full; A/V slice cols [8*mblk, 8*mblk+8); beta
        const int f = tid * 8;
        const int t = f >> 6, off = f & 63;
        const int row = ((g * NCH + t) * NH + hh) * 64 + off;
        *(float4*)&K_l[t][off]     = *(const float4*)(K + row);
        *(float4*)&K_l[t][off + 4] = *(const float4*)(K + row + 4);
        const int t2 = tid >> 3, c = tid & 7;
        const int row2 = ((g * NCH + t2) * NH + hh) * 64 + 8 * mblk + c;
        A_l[t2][c] = A_bar[row2];
        V_l[t2][c] = V[row2];
        if (tid < NCH) b_l[tid] = beta[(g * NCH + tid) * NH + hh];
        __syncthreads();
    }

    // ---- prefix for this m, software-pipelined (load gg+1 while folding gg) ----
    float hr = 0.f, hi = 0.f;
    if (g > 0) {
        int e = (0 * NH + hh) * NM + m;
        float ar = totalA[2 * e], ai = totalA[2 * e + 1];
        float fr = buf[e * 128 + lane], fi = buf[e * 128 + 64 + lane];
        for (int gg = 1; gg < g; ++gg) {
            const int e2 = (gg * NH + hh) * NM + m;
            const float ar2 = totalA[2 * e2], ai2 = totalA[2 * e2 + 1];
            const float fr2 = buf[e2 * 128 + lane], fi2 = buf[e2 * 128 + 64 + lane];
            const float n = ar * hr - ai * hi + fr;
            hi = ar * hi + ai * hr + fi;
            hr = n;
            ar = ar2; ai = ai2; fr = fr2; fi = fi2;
        }
        const float n = ar * hr - ai * hi + fr;
        hi = ar * hi + ai * hr + fi;
        hr = n;
    }

    // ---- final scan with init = s_in; state IS the output ----
    const int base_l = g * NCH;
    const int c0 = 2 * wv;
#pragma unroll 8
    for (int t = 0; t < NCH; ++t) {
        const float kd = K_l[t][lane];
        const float b  = b_l[t];
        const float ar = A_l[t][c0], ai = A_l[t][c0 + 1];
        const float vr = V_l[t][c0], vi = V_l[t][c0 + 1];
        const float bk = b * kd;

        const float hkr = wave_sum_bcast(hr * kd);
        const float hki = wave_sum_bcast(hi * kd);

        const float tr = hr - bk * hkr, ti = hi - bk * hki;
        hr = ar * tr - ai * ti + bk * vr;
        hi = ar * ti + ai * tr + bk * vi;

        // Y[b,l,h,2m,d]=Re, Y[b,l,h,2m+1,d]=Im — 256 B/wave contiguous stores
        const int ybase = ((base_l + t) * NH + hh) * (2 * NM) * ND + lane;
        __builtin_nontemporal_store(hr, &Y[ybase + (2 * m) * ND]);
        __builtin_nontemporal_store(hi, &Y[ybase + (2 * m + 1) * ND]);
    }
}

extern "C" void kernel_launch(void* const* d_in, const int* in_sizes, int n_in,
                              void* d_out, int out_size, void* d_ws, size_t ws_size,
                              hipStream_t stream) {
    const float* A_bar = (const float*)d_in[0];
    const float* K     = (const float*)d_in[1];
    const float* V     = (const float*)d_in[2];
    const float* beta  = (const float*)d_in[3];
    float* Y = (float*)d_out;

    float* ws = (float*)d_ws;
    float* totalA = ws;                 // NC*NH*NM*2 = 16384 floats
    float* buf    = ws + 16384;         // finalH planar: 1,048,576 floats (4 MB)

    intra_kernel<<<(NC - 1) * NH, 512, 0, stream>>>(A_bar, K, V, beta, totalA, buf);
    final_kernel<<<NC * NH * 8, 256, 0, stream>>>(A_bar, K, V, beta, totalA, buf, Y);
}

// Round 25
// 43.272 us; speedup vs baseline: 1.1200x; 1.0187x over previous
//
#include <hip/hip_runtime.h>

#define NH 8
#define ND 64
#define NM 32
#define NCH 32   // sub-chunk size
#define NC 32    // num sub-chunks

typedef float f32x4 __attribute__((ext_vector_type(4)));

// ---- 16-lane-group allreduce, pure VALU butterfly (no readlane) ----
__device__ __forceinline__ float grp16_sum(float x) {
    x += __int_as_float(__builtin_amdgcn_update_dpp(0, __float_as_int(x), 0xB1, 0xf, 0xf, false));
    x += __int_as_float(__builtin_amdgcn_update_dpp(0, __float_as_int(x), 0x4E, 0xf, 0xf, false));
    x += __int_as_float(__builtin_amdgcn_update_dpp(0, __float_as_int(x), 0x141, 0xf, 0xf, false));
    x += __int_as_float(__builtin_amdgcn_update_dpp(0, __float_as_int(x), 0x140, 0xf, 0xf, false));
    return x;
}

// ---- 64-lane reduce (DPP rows + readlane bcast) ----
__device__ __forceinline__ float wave_sum_bcast(float x) {
    float s = x;
    s += __int_as_float(__builtin_amdgcn_update_dpp(0, __float_as_int(s), 0x111, 0xf, 0xf, false));
    s += __int_as_float(__builtin_amdgcn_update_dpp(0, __float_as_int(s), 0x112, 0xf, 0xf, false));
    s += __int_as_float(__builtin_amdgcn_update_dpp(0, __float_as_int(s), 0x114, 0xf, 0xf, false));
    s += __int_as_float(__builtin_amdgcn_update_dpp(0, __float_as_int(s), 0x118, 0xf, 0xf, false));
    s += __int_as_float(__builtin_amdgcn_update_dpp(0, __float_as_int(s), 0x142, 0xa, 0xf, false));
    s += __int_as_float(__builtin_amdgcn_update_dpp(0, __float_as_int(s), 0x143, 0xc, 0xf, false));
    return __int_as_float(__builtin_amdgcn_readlane(__float_as_int(s), 63));
}

// ---------------- Kernel A: intra scan, 16-lane groups, lane j owns d=4j..4j+3 ----------------
// 248 blocks x 512 threads = one (g,hh) chunk per block (g=31's summary never consumed).
__global__ __launch_bounds__(512) void intra_kernel(
    const float* __restrict__ A_bar, const float* __restrict__ K,
    const float* __restrict__ V, const float* __restrict__ beta,
    float* __restrict__ totalA, float* __restrict__ buf)
{
    __shared__ float K_l[NCH][ND], A_l[NCH][ND], V_l[NCH][ND], b_l[NCH];
    const int gh = blockIdx.x;       // g*NH + hh
    const int hh = gh & (NH - 1);
    const int g  = gh >> 3;
    const int tid = threadIdx.x;

    {   // stage (512 float4 stagers)
        const int f = tid * 4;
        const int t = f >> 6, off = f & 63;
        const int row = ((g * NCH + t) * NH + hh) * 64 + off;
        *(float4*)&K_l[t][off] = *(const float4*)(K + row);
        *(float4*)&A_l[t][off] = *(const float4*)(A_bar + row);
        *(float4*)&V_l[t][off] = *(const float4*)(V + row);
        if (tid < NCH) b_l[tid] = beta[(g * NCH + tid) * NH + hh];
        __syncthreads();
    }

    const int lane = tid & 63;
    const int r = lane >> 4, j = lane & 15;
    const int m = (tid >> 6) * 4 + r;            // 0..31

    float hr0 = 0.f, hr1 = 0.f, hr2 = 0.f, hr3 = 0.f;
    float hi0 = 0.f, hi1 = 0.f, hi2 = 0.f, hi3 = 0.f;
    float cr = 1.f, ci = 0.f;

#pragma unroll 4
    for (int t = 0; t < NCH; ++t) {
        const float4 k4 = *(const float4*)(&K_l[t][4 * j]);
        const float2 a2 = *(const float2*)(&A_l[t][2 * m]);
        const float2 v2 = *(const float2*)(&V_l[t][2 * m]);
        const float  b  = b_l[t];

        float sr = (hr0 * k4.x + hr1 * k4.y) + (hr2 * k4.z + hr3 * k4.w);
        float si = (hi0 * k4.x + hi1 * k4.y) + (hi2 * k4.z + hi3 * k4.w);
        sr = grp16_sum(sr);
        si = grp16_sum(si);

        const float bk0 = b * k4.x, bk1 = b * k4.y, bk2 = b * k4.z, bk3 = b * k4.w;
        float tr, ti;
        tr = hr0 - bk0 * sr; ti = hi0 - bk0 * si;
        hr0 = a2.x * tr - a2.y * ti + bk0 * v2.x;
        hi0 = a2.x * ti + a2.y * tr + bk0 * v2.y;
        tr = hr1 - bk1 * sr; ti = hi1 - bk1 * si;
        hr1 = a2.x * tr - a2.y * ti + bk1 * v2.x;
        hi1 = a2.x * ti + a2.y * tr + bk1 * v2.y;
        tr = hr2 - bk2 * sr; ti = hi2 - bk2 * si;
        hr2 = a2.x * tr - a2.y * ti + bk2 * v2.x;
        hi2 = a2.x * ti + a2.y * tr + bk2 * v2.y;
        tr = hr3 - bk3 * sr; ti = hi3 - bk3 * si;
        hr3 = a2.x * tr - a2.y * ti + bk3 * v2.x;
        hi3 = a2.x * ti + a2.y * tr + bk3 * v2.y;

        const float n = cr * a2.x - ci * a2.y;
        ci = cr * a2.y + ci * a2.x;
        cr = n;
    }

    const int base_m = gh * NM + m;              // entry id
    *(float4*)&buf[base_m * 128 + 4 * j]      = make_float4(hr0, hr1, hr2, hr3);
    *(float4*)&buf[base_m * 128 + 64 + 4 * j] = make_float4(hi0, hi1, hi2, hi3);
    if (j == 0) {
        totalA[2 * base_m]     = cr;
        totalA[2 * base_m + 1] = ci;
    }
}

// ---------------- Kernel B: single-m 64-lane waves, prefix + final scan ----------------
// 2048 blocks x 256 threads (8 blocks/CU, 32 waves/CU); wave = one m-row.
__global__ __launch_bounds__(256) void final_kernel(
    const float* __restrict__ A_bar, const float* __restrict__ K,
    const float* __restrict__ V, const float* __restrict__ beta,
    const float* __restrict__ totalA, const float* __restrict__ buf,
    float* __restrict__ Y)
{
    __shared__ float K_l[NCH][ND];
    __shared__ float A_l[NCH][8], V_l[NCH][8];
    __shared__ float b_l[NCH];

    const int blk  = blockIdx.x;         // 0..2047
    const int gh   = blk >> 3;           // g*NH + hh
    const int mblk = blk & 7;
    const int hh   = gh & (NH - 1);
    const int g    = gh >> 3;
    const int tid  = threadIdx.x;
    const int wv   = tid >> 6;
    const int lane = tid & 63;
    const int m    = mblk * 4 + wv;

    {   // stage: K full; A/V slice cols [8*mblk, 8*mblk+8); beta
        const int f = tid * 8;
        const int t = f >> 6, off = f & 63;
        const int row = ((g * NCH + t) * NH + hh) * 64 + off;
        *(float4*)&K_l[t][off]     = *(const float4*)(K + row);
        *(float4*)&K_l[t][off + 4] = *(const float4*)(K + row + 4);
        const int t2 = tid >> 3, c = tid & 7;
        const int row2 = ((g * NCH + t2) * NH + hh) * 64 + 8 * mblk + c;
        A_l[t2][c] = A_bar[row2];
        V_l[t2][c] = V[row2];
        if (tid < NCH) b_l[tid] = beta[(g * NCH + tid) * NH + hh];
        __syncthreads();
    }

    // ---- prefix for this m: fold s = A_gg * s + H_gg over gg < g ----
    float hr = 0.f, hi = 0.f;
    for (int gg = 0; gg < g; ++gg) {
        const int e = (gg * NH + hh) * NM + m;
        const float ar = totalA[2 * e], ai = totalA[2 * e + 1];
        const float fr = buf[e * 128 + lane];
        const float fi = buf[e * 128 + 64 + lane];
        const float n = ar * hr - ai * hi + fr;
        hi = ar * hi + ai * hr + fi;
        hr = n;
    }

    // ---- final scan with init = s_in; state IS the output ----
    const int base_l = g * NCH;
    const int c0 = 2 * wv;
#pragma unroll 4
    for (int t = 0; t < NCH; ++t) {
        const float kd = K_l[t][lane];
        const float b  = b_l[t];
        const float ar = A_l[t][c0], ai = A_l[t][c0 + 1];
        const float vr = V_l[t][c0], vi = V_l[t][c0 + 1];
        const float bk = b * kd;

        const float hkr = wave_sum_bcast(hr * kd);
        const float hki = wave_sum_bcast(hi * kd);

        const float tr = hr - bk * hkr, ti = hi - bk * hki;
        hr = ar * tr - ai * ti + bk * vr;
        hi = ar * ti + ai * tr + bk * vi;

        // Y[b,l,h,2m,d]=Re, Y[b,l,h,2m+1,d]=Im — 256 B/wave contiguous stores
        const int ybase = ((base_l + t) * NH + hh) * (2 * NM) * ND + lane;
        __builtin_nontemporal_store(hr, &Y[ybase + (2 * m) * ND]);
        __builtin_nontemporal_store(hi, &Y[ybase + (2 * m + 1) * ND]);
    }
}

extern "C" void kernel_launch(void* const* d_in, const int* in_sizes, int n_in,
                              void* d_out, int out_size, void* d_ws, size_t ws_size,
                              hipStream_t stream) {
    const float* A_bar = (const float*)d_in[0];
    const float* K     = (const float*)d_in[1];
    const float* V     = (const float*)d_in[2];
    const float* beta  = (const float*)d_in[3];
    float* Y = (float*)d_out;

    float* ws = (float*)d_ws;
    float* totalA = ws;                 // NC*NH*NM*2 = 16384 floats
    float* buf    = ws + 16384;         // finalH planar: 1,048,576 floats (4 MB)

    intra_kernel<<<(NC - 1) * NH, 512, 0, stream>>>(A_bar, K, V, beta, totalA, buf);
    final_kernel<<<NC * NH * 8, 256, 0, stream>>>(A_bar, K, V, beta, totalA, buf, Y);
}